// Round 1
// baseline (1139.841 us; speedup 1.0000x reference)
//
#include <hip/hip_runtime.h>
#include <math.h>

// ---------------- problem constants ----------------
#define BB 8
#define LL 8192
#define DD 128
#define NCH 8
#define NST 64
#define TAPS 32          // e^{-0.5*32} ~ 1e-7 relative: FIR truncation far below threshold
#define NOUTD 375

// ---------------- workspace layout (floats) ----------------
static constexpr size_t WS_H      = 0;                          // [B,L,128] residual stream
static constexpr size_t WS_Z      = WS_H      + (size_t)BB*LL*DD; // [B,L,128] in-proj output
static constexpr size_t WS_LOGITS = WS_Z      + (size_t)BB*LL*DD; // [B,L]
static constexpr size_t WS_SEGM   = WS_LOGITS + (size_t)BB*LL;    // [B,16] segment max
static constexpr size_t WS_SEGS   = WS_SEGM   + BB*16;            // [B,16] segment expsum
static constexpr size_t WS_SEGV   = WS_SEGS   + BB*16;            // [B,16,128] segment weighted h
static constexpr size_t WS_SCALE  = WS_SEGV   + (size_t)BB*16*DD; // [7,B,128]
static constexpr size_t WS_SHIFT  = WS_SCALE  + (size_t)7*BB*DD;  // [7,B,128]
static constexpr size_t WS_WG     = WS_SHIFT  + (size_t)7*BB*DD;  // [3,128,128] g-folded in-proj W
static constexpr size_t WS_C1     = WS_WG     + (size_t)3*DD*DD;  // [3,128] sum_k g_k W_kd
static constexpr size_t WS_C2     = WS_C1     + 3*DD;             // [3,128] sum_k b_k W_kd + inb
static constexpr size_t WS_KTAB   = WS_C2     + 3*DD;             // [3,8,32] FIR taps
static constexpr size_t WS_GAW    = WS_KTAB   + 3*NCH*TAPS;       // [128] attn_g*attn_w
static constexpr size_t WS_ASCAL  = WS_GAW    + DD;               // c1s, c2s (padded to 32)
static constexpr size_t WS_BASE   = WS_ASCAL  + 32;               // [B,128] folded singer/lang/inb
static constexpr size_t WS_TOTAL  = WS_BASE   + BB*DD;            // ~16.93M floats = 67.7 MB

__device__ __forceinline__ float silu_f(float x){ return x / (1.f + expf(-x)); }

// ================= K0: fold weights, tabulate FIR taps =================
__global__ __launch_bounds__(256) void k0_setup(
    const float* s4_ln_g, const float* s4_ln_b, const float* s4_inW, const float* s4_inb,
    const float* lam_re, const float* lam_im, const float* Bn, const float* Cre, const float* Cim,
    const float* attn_g, const float* attn_lnb, const float* attn_w, const float* attn_bias,
    const int* singer_id, const int* language_id,
    const float* singer_emb, const float* lang_emb, const float* inW, const float* inb,
    float* ws)
{
  int blk = blockIdx.x, tid = threadIdx.x;
  if (blk < 3) {
    int ly = blk;
    if (tid < DD) {
      int d = tid;
      float c1 = 0.f, c2 = 0.f;
      for (int k = 0; k < DD; ++k) {
        float g = s4_ln_g[ly*DD + k];
        float b = s4_ln_b[ly*DD + k];
        float w = s4_inW[((size_t)ly*DD + k)*DD + d];
        ws[WS_WG + ((size_t)ly*DD + k)*DD + d] = g * w;
        c1 += g * w;
        c2 += b * w;
      }
      ws[WS_C1 + ly*DD + d] = c1;
      ws[WS_C2 + ly*DD + d] = c2 + s4_inb[ly*DD + d];
    }
    {  // FIR taps: 256 threads = 8 chunks x 32 taps
      int c = tid >> 5, dt = tid & 31;
      const float* lre = lam_re + (ly*NCH + c)*NST;
      const float* lim = lam_im + (ly*NCH + c)*NST;
      const float* bn  = Bn  + (ly*NCH + c)*NST;
      const float* cre = Cre + (ly*NCH + c)*NST;
      const float* cim = Cim + (ly*NCH + c)*NST;
      float td = (float)dt, acc = 0.f;
      for (int n = 0; n < NST; ++n) {
        float e = expf(lre[n]*td);
        float ang = lim[n]*td;
        acc += bn[n]*(cre[n]*cosf(ang) - cim[n]*sinf(ang))*e;
      }
      ws[WS_KTAB + (ly*NCH + c)*TAPS + dt] = acc;
    }
    if (ly == 0 && tid < DD) ws[WS_GAW + tid] = attn_g[tid]*attn_w[tid];
    if (ly == 0 && tid == 0) {
      float c1s = 0.f, c2s = 0.f;
      for (int d = 0; d < DD; ++d) { c1s += attn_g[d]*attn_w[d]; c2s += attn_lnb[d]*attn_w[d]; }
      ws[WS_ASCAL+0] = c1s;
      ws[WS_ASCAL+1] = c2s + attn_bias[0];
    }
  } else {
    // per-batch base[b][d] = inb + singer/lang embedding contributions
    for (int o = tid; o < BB*DD; o += 256) {
      int b = o >> 7, d = o & 127;
      int sid = singer_id[b], lid = language_id[b];
      float acc = inb[d];
      for (int j = 0; j < 32; ++j) acc += singer_emb[sid*32 + j]*inW[(64 + j)*DD + d];
      for (int j = 0; j < 16; ++j) acc += lang_emb[lid*16 + j]*inW[(96 + j)*DD + d];
      ws[WS_BASE + o] = acc;
    }
  }
}

// ================= K1: embed + input proj + LN + SiLU -> h =================
__global__ __launch_bounds__(256) void k1_input(
    const int* phone_seq, const float* f0, const float* phone_emb,
    const float* inW, const float* inln_g, const float* inln_b, float* ws)
{
  __shared__ __align__(16) float pm[64*72];
  __shared__ int   ps[64];
  __shared__ float fv[64];
  int tid = threadIdx.x;
  size_t gbase = (size_t)blockIdx.x * 64;   // 64-token tile (never crosses b: 8192%64==0)
  if (tid < 64) { ps[tid] = phone_seq[gbase + tid]; fv[tid] = f0[gbase + tid]; }
  __syncthreads();
  #pragma unroll
  for (int j = 0; j < 4; ++j) {
    int idx4 = tid + 256*j;                 // 0..1023 = 64 tok x 16 float4
    int tok = idx4 >> 4, col = idx4 & 15;
    float4 v = *(const float4*)(phone_emb + (size_t)ps[tok]*64 + col*4);
    *(float4*)(pm + tok*72 + col*4) = v;
  }
  __syncthreads();
  int ti = tid >> 5, di = tid & 31, d0 = di*4;
  float acc[8][4];
  #pragma unroll
  for (int i = 0; i < 8; ++i) { acc[i][0]=0.f; acc[i][1]=0.f; acc[i][2]=0.f; acc[i][3]=0.f; }
  for (int kk = 0; kk < 64; kk += 4) {
    float4 w0 = *(const float4*)(inW + (kk+0)*DD + d0);
    float4 w1 = *(const float4*)(inW + (kk+1)*DD + d0);
    float4 w2 = *(const float4*)(inW + (kk+2)*DD + d0);
    float4 w3 = *(const float4*)(inW + (kk+3)*DD + d0);
    #pragma unroll
    for (int i = 0; i < 8; ++i) {
      float4 a = *(float4*)(pm + (ti*8 + i)*72 + kk);
      acc[i][0] += a.x*w0.x + a.y*w1.x + a.z*w2.x + a.w*w3.x;
      acc[i][1] += a.x*w0.y + a.y*w1.y + a.z*w2.y + a.w*w3.y;
      acc[i][2] += a.x*w0.z + a.y*w1.z + a.z*w2.z + a.w*w3.z;
      acc[i][3] += a.x*w0.w + a.y*w1.w + a.z*w2.w + a.w*w3.w;
    }
  }
  float4 w112 = *(const float4*)(inW + 112*DD + d0);
  int b = (int)(gbase >> 13);
  float4 bs  = *(const float4*)(ws + WS_BASE + b*DD + d0);
  float4 lg4 = *(const float4*)(inln_g + d0);
  float4 lb4 = *(const float4*)(inln_b + d0);
  #pragma unroll
  for (int i = 0; i < 8; ++i) {
    int tok = ti*8 + i;
    float fz = fv[tok];
    float y0 = acc[i][0] + fz*w112.x + bs.x;
    float y1 = acc[i][1] + fz*w112.y + bs.y;
    float y2 = acc[i][2] + fz*w112.z + bs.z;
    float y3 = acc[i][3] + fz*w112.w + bs.w;
    float s  = y0+y1+y2+y3;
    float ss = y0*y0+y1*y1+y2*y2+y3*y3;
    #pragma unroll
    for (int m = 16; m >= 1; m >>= 1) { s += __shfl_xor(s, m); ss += __shfl_xor(ss, m); }
    float mean = s * 0.0078125f;
    float var  = ss * 0.0078125f - mean*mean;
    float rstd = rsqrtf(var + 1e-5f);
    y0 = silu_f((y0 - mean)*rstd*lg4.x + lb4.x);
    y1 = silu_f((y1 - mean)*rstd*lg4.y + lb4.y);
    y2 = silu_f((y2 - mean)*rstd*lg4.z + lb4.z);
    y3 = silu_f((y3 - mean)*rstd*lg4.w + lb4.w);
    *(float4*)(ws + WS_H + (gbase + tok)*DD + d0) = make_float4(y0,y1,y2,y3);
  }
}

// ================= K2: folded LN + in_proj -> z =================
__global__ __launch_bounds__(256) void k2_ln_inproj(float* ws, int ly)
{
  __shared__ __align__(16) float hm[64*136];
  __shared__ float mrs_s[64], rs_s[64];
  int tid = threadIdx.x;
  size_t gbase = (size_t)blockIdx.x * 64;
  const float* hbuf = ws + WS_H;
  float s[8], ss[8];
  #pragma unroll
  for (int j = 0; j < 8; ++j) {
    int idx4 = tid + 256*j;                 // 0..2047 = 64 tok x 32 float4
    int tok = idx4 >> 5, c4 = idx4 & 31;
    float4 v = *(const float4*)(hbuf + gbase*DD + (size_t)idx4*4);
    *(float4*)(hm + tok*136 + c4*4) = v;
    s[j]  = v.x+v.y+v.z+v.w;
    ss[j] = v.x*v.x+v.y*v.y+v.z*v.z+v.w*v.w;
  }
  #pragma unroll
  for (int m = 16; m >= 1; m >>= 1) {
    #pragma unroll
    for (int j = 0; j < 8; ++j) { s[j] += __shfl_xor(s[j], m); ss[j] += __shfl_xor(ss[j], m); }
  }
  if ((tid & 31) == 0) {
    #pragma unroll
    for (int j = 0; j < 8; ++j) {
      int tok = (tid >> 5) + 8*j;
      float mean = s[j]*0.0078125f;
      float var  = ss[j]*0.0078125f - mean*mean;
      float rstd = rsqrtf(var + 1e-5f);
      rs_s[tok] = rstd; mrs_s[tok] = mean*rstd;
    }
  }
  __syncthreads();
  int ti = tid >> 5, di = tid & 31, d0 = di*4;
  const float* Wg = ws + WS_WG + (size_t)ly*DD*DD;
  float acc[8][4];
  #pragma unroll
  for (int i = 0; i < 8; ++i) { acc[i][0]=0.f; acc[i][1]=0.f; acc[i][2]=0.f; acc[i][3]=0.f; }
  for (int kk = 0; kk < DD; kk += 4) {
    float4 w0 = *(const float4*)(Wg + (kk+0)*DD + d0);
    float4 w1 = *(const float4*)(Wg + (kk+1)*DD + d0);
    float4 w2 = *(const float4*)(Wg + (kk+2)*DD + d0);
    float4 w3 = *(const float4*)(Wg + (kk+3)*DD + d0);
    #pragma unroll
    for (int i = 0; i < 8; ++i) {
      float4 a = *(float4*)(hm + (ti*8 + i)*136 + kk);
      acc[i][0] += a.x*w0.x + a.y*w1.x + a.z*w2.x + a.w*w3.x;
      acc[i][1] += a.x*w0.y + a.y*w1.y + a.z*w2.y + a.w*w3.y;
      acc[i][2] += a.x*w0.z + a.y*w1.z + a.z*w2.z + a.w*w3.z;
      acc[i][3] += a.x*w0.w + a.y*w1.w + a.z*w2.w + a.w*w3.w;
    }
  }
  float4 c1 = *(const float4*)(ws + WS_C1 + ly*DD + d0);
  float4 c2 = *(const float4*)(ws + WS_C2 + ly*DD + d0);
  float* zbuf = ws + WS_Z;
  #pragma unroll
  for (int i = 0; i < 8; ++i) {
    int tok = ti*8 + i;
    float rstd = rs_s[tok], mrs = mrs_s[tok];
    float4 o;
    o.x = rstd*acc[i][0] - mrs*c1.x + c2.x;
    o.y = rstd*acc[i][1] - mrs*c1.y + c2.y;
    o.z = rstd*acc[i][2] - mrs*c1.z + c2.z;
    o.w = rstd*acc[i][3] - mrs*c1.w + c2.w;
    *(float4*)(zbuf + (gbase + tok)*DD + d0) = o;
  }
}

// ================= K3: 64-tap bidirectional FIR + skip + out_proj + SiLU + residual (+logits) ===
__global__ __launch_bounds__(256) void k3_conv_out(
    float* ws, const float* s4_outW, const float* s4_outb, const float* Dc, int ly, int do_logits)
{
  __shared__ __align__(16) float zw[96*128];   // 32-token tile + 32-token halo each side
  __shared__ __align__(16) float ym[32*136];
  __shared__ float k2t[8*64];
  __shared__ float dcs[8];
  int tid = threadIdx.x, blk = blockIdx.x;
  int b  = blk >> 8;             // 256 tiles of 32 per sequence
  int t0 = (blk & 255) * 32;
  const float* zbuf = ws + WS_Z;
  #pragma unroll
  for (int j = 0; j < 12; ++j) {
    int idx4 = tid + 256*j;      // 0..3071 = 96 tok x 32 float4
    int w = idx4 >> 5, c4 = idx4 & 31;
    int t = t0 - 32 + w;
    float4 v = make_float4(0.f,0.f,0.f,0.f);
    if (t >= 0 && t < LL) v = *(const float4*)(zbuf + ((size_t)b*LL + t)*DD + c4*4);
    *(float4*)(zw + w*128 + c4*4) = v;
  }
  for (int o = tid; o < 512; o += 256) {       // K2[j] table: j=-31..32 -> m=0..63
    int c = o >> 6, m = o & 63;
    int idx = (m <= 31) ? (31 - m) : (m - 32);
    k2t[o] = ws[WS_KTAB + (ly*NCH + c)*TAPS + idx];
  }
  if (tid < 8) dcs[tid] = Dc[ly*NCH + tid];
  __syncthreads();
  // conv: thread = (half of 16 tokens, channel)
  {
    int half = tid >> 7, ch = tid & 127, c = ch >> 4;
    int base = 1 + half*16;                    // window index of tap window start
    float ring[16], accv[16];
    #pragma unroll
    for (int x = 0; x < 16; ++x) { ring[x] = zw[(base + x)*128 + ch]; accv[x] = 0.f; }
    #pragma unroll
    for (int m = 0; m < 64; ++m) {
      float kf = k2t[c*64 + m];
      #pragma unroll
      for (int i = 0; i < 16; ++i) accv[i] += kf * ring[(m + i) & 15];
      if (m < 63) ring[m & 15] = zw[(base + m + 16)*128 + ch];
    }
    float dcv = dcs[c];
    #pragma unroll
    for (int i = 0; i < 16; ++i) {
      int tloc = half*16 + i;
      ym[tloc*136 + ch] = accv[i] + dcv * zw[(32 + tloc)*128 + ch];
    }
  }
  __syncthreads();
  // out_proj on y tile
  int ti = tid >> 5, di = tid & 31, d0 = di*4;
  const float* Wo = s4_outW + (size_t)ly*DD*DD;
  float acc[4][4];
  #pragma unroll
  for (int i = 0; i < 4; ++i) { acc[i][0]=0.f; acc[i][1]=0.f; acc[i][2]=0.f; acc[i][3]=0.f; }
  for (int kk = 0; kk < DD; kk += 4) {
    float4 w0 = *(const float4*)(Wo + (kk+0)*DD + d0);
    float4 w1 = *(const float4*)(Wo + (kk+1)*DD + d0);
    float4 w2 = *(const float4*)(Wo + (kk+2)*DD + d0);
    float4 w3 = *(const float4*)(Wo + (kk+3)*DD + d0);
    #pragma unroll
    for (int i = 0; i < 4; ++i) {
      float4 a = *(float4*)(ym + (ti*4 + i)*136 + kk);
      acc[i][0] += a.x*w0.x + a.y*w1.x + a.z*w2.x + a.w*w3.x;
      acc[i][1] += a.x*w0.y + a.y*w1.y + a.z*w2.y + a.w*w3.y;
      acc[i][2] += a.x*w0.z + a.y*w1.z + a.z*w2.z + a.w*w3.z;
      acc[i][3] += a.x*w0.w + a.y*w1.w + a.z*w2.w + a.w*w3.w;
    }
  }
  float4 ob = *(const float4*)(s4_outb + ly*DD + d0);
  float* hbuf = ws + WS_H;
  float4 gw = make_float4(0.f,0.f,0.f,0.f);
  float c1s = 0.f, c2s = 0.f;
  if (do_logits) {
    gw = *(const float4*)(ws + WS_GAW + d0);
    c1s = ws[WS_ASCAL+0]; c2s = ws[WS_ASCAL+1];
  }
  #pragma unroll
  for (int i = 0; i < 4; ++i) {
    int tok = ti*4 + i;
    size_t gofs = ((size_t)b*LL + t0 + tok)*DD + d0;
    float4 hold = *(const float4*)(hbuf + gofs);
    float4 hn;
    hn.x = hold.x + silu_f(acc[i][0] + ob.x);
    hn.y = hold.y + silu_f(acc[i][1] + ob.y);
    hn.z = hold.z + silu_f(acc[i][2] + ob.z);
    hn.w = hold.w + silu_f(acc[i][3] + ob.w);
    *(float4*)(hbuf + gofs) = hn;
    if (do_logits) {   // fused attention LN+dot on final h
      float s  = hn.x + hn.y + hn.z + hn.w;
      float ss = hn.x*hn.x + hn.y*hn.y + hn.z*hn.z + hn.w*hn.w;
      float dt = hn.x*gw.x + hn.y*gw.y + hn.z*gw.z + hn.w*gw.w;
      #pragma unroll
      for (int m = 16; m >= 1; m >>= 1) {
        s += __shfl_xor(s, m); ss += __shfl_xor(ss, m); dt += __shfl_xor(dt, m);
      }
      if (di == 0) {
        float mean = s*0.0078125f;
        float var  = ss*0.0078125f - mean*mean;
        float rstd = rsqrtf(var + 1e-5f);
        ws[WS_LOGITS + (size_t)b*LL + t0 + tok] = rstd*dt - mean*rstd*c1s + c2s;
      }
    }
  }
}

// ================= K5b: segmented softmax + weighted pool partials =================
__global__ __launch_bounds__(256) void k5b_pool(float* ws)
{
  int blk = blockIdx.x, tid = threadIdx.x;
  int b = blk >> 4, seg = blk & 15;                  // 16 segments of 512 per batch
  const float* lg = ws + WS_LOGITS + (size_t)b*LL + seg*512;
  __shared__ float ev[512];
  __shared__ float red[4], red2[4];
  __shared__ float vr[2][128];
  float a0 = lg[tid], a1 = lg[tid + 256];
  float mx = fmaxf(a0, a1);
  #pragma unroll
  for (int m = 32; m >= 1; m >>= 1) mx = fmaxf(mx, __shfl_xor(mx, m));
  if ((tid & 63) == 0) red[tid >> 6] = mx;
  __syncthreads();
  float M = fmaxf(fmaxf(red[0], red[1]), fmaxf(red[2], red[3]));
  float e0 = expf(a0 - M), e1 = expf(a1 - M);
  ev[tid] = e0; ev[tid + 256] = e1;
  float s = e0 + e1;
  #pragma unroll
  for (int m = 32; m >= 1; m >>= 1) s += __shfl_xor(s, m);
  if ((tid & 63) == 0) red2[tid >> 6] = s;
  __syncthreads();
  float S = red2[0] + red2[1] + red2[2] + red2[3];
  int ls = tid >> 7, d = tid & 127;
  const float* hb = ws + WS_H + ((size_t)b*LL + seg*512)*DD;
  float acc = 0.f;
  for (int jj = 0; jj < 256; ++jj) {
    int tok = jj*2 + ls;
    acc += ev[tok] * hb[(size_t)tok*DD + d];
  }
  vr[ls][d] = acc;
  __syncthreads();
  if (tid < 128) ws[WS_SEGV + (size_t)(b*16 + seg)*DD + tid] = vr[0][tid] + vr[1][tid];
  if (tid == 0) { ws[WS_SEGM + b*16 + seg] = M; ws[WS_SEGS + b*16 + seg] = S; }
}

// ================= K5c: combine pool, g, FiLM scale/shift =================
__global__ __launch_bounds__(256) void k5c_cond(
    float* ws, const float* gpW, const float* gpb,
    const float* genW_s, const float* genb_s, const float* genW_sh, const float* genb_sh)
{
  __shared__ float gpre[BB*DD];
  __shared__ float gg[BB*32];
  __shared__ float Ms[BB], Ss[BB];
  int tid = threadIdx.x;
  if (tid < BB) {
    int b = tid;
    float M = -1e30f;
    for (int sg = 0; sg < 16; ++sg) M = fmaxf(M, ws[WS_SEGM + b*16 + sg]);
    float S = 0.f;
    for (int sg = 0; sg < 16; ++sg) S += ws[WS_SEGS + b*16 + sg]*expf(ws[WS_SEGM + b*16 + sg] - M);
    Ms[b] = M; Ss[b] = S;
  }
  __syncthreads();
  for (int o = tid; o < BB*DD; o += 256) {
    int b = o >> 7, d = o & 127;
    float V = 0.f;
    for (int sg = 0; sg < 16; ++sg)
      V += ws[WS_SEGV + (size_t)(b*16 + sg)*DD + d]*expf(ws[WS_SEGM + b*16 + sg] - Ms[b]);
    gpre[o] = V / Ss[b];
  }
  __syncthreads();
  {
    int b = tid >> 5, c = tid & 31;
    float acc = gpb[c];
    for (int k = 0; k < DD; ++k) acc += gpre[b*DD + k]*gpW[k*32 + c];
    gg[tid] = acc;
  }
  __syncthreads();
  for (int o = tid; o < 7*BB*DD; o += 256) {
    int hd = o >> 10, r = o & 1023, b = r >> 7, d = r & 127;
    float sc = genb_s[hd*DD + d], sh = genb_sh[hd*DD + d];
    for (int c = 0; c < 32; ++c) {
      float g = gg[b*32 + c];
      sc += g*genW_s[((size_t)hd*32 + c)*DD + d];
      sh += g*genW_sh[((size_t)hd*32 + c)*DD + d];
    }
    ws[WS_SCALE + o] = sc;
    ws[WS_SHIFT + o] = sh;
  }
}

// ================= K6: 7 FiLM generator heads =================
__device__ __constant__ int c_offs[7] = {0, 1, 2, 102, 294, 358, 370};
__device__ __constant__ int c_dims[7] = {1, 1, 100, 192, 64, 12, 5};

__global__ __launch_bounds__(256) void k6_heads(
    float* ws, const float* genW_h, const float* genb_h,
    const float* genW_o, const float* genb_o, float* out)
{
  __shared__ __align__(16) float hm[32*136];
  __shared__ __align__(16) float am[32*136];
  __shared__ __align__(16) float rm[32*72];
  __shared__ __align__(16) float sc[128], sh[128];
  int tid = threadIdx.x, blk = blockIdx.x;
  int b = blk >> 8, t0 = (blk & 255)*32;
  const float* hb = ws + WS_H + ((size_t)b*LL + t0)*DD;
  #pragma unroll
  for (int j = 0; j < 4; ++j) {
    int idx4 = tid + 256*j;                 // 32 tok x 32 float4
    int tok = idx4 >> 5, c4 = idx4 & 31;
    *(float4*)(hm + tok*136 + c4*4) = *(const float4*)(hb + (size_t)idx4*4);
  }
  for (int hd = 0; hd < 7; ++hd) {
    __syncthreads();                        // protects sc/sh/am/rm reuse (and first-iter hm load)
    if (tid < 128)      sc[tid]     = ws[WS_SCALE + hd*BB*DD + b*DD + tid];
    else                sh[tid-128] = ws[WS_SHIFT + hd*BB*DD + b*DD + (tid-128)];
    __syncthreads();
    #pragma unroll
    for (int j = 0; j < 4; ++j) {
      int idx4 = tid + 256*j;
      int tok = idx4 >> 5, c0 = (idx4 & 31)*4;
      float4 h4 = *(float4*)(hm + tok*136 + c0);
      float4 s4 = *(float4*)(sc + c0);
      float4 t4 = *(float4*)(sh + c0);
      *(float4*)(am + tok*136 + c0) =
          make_float4(h4.x*s4.x + t4.x, h4.y*s4.y + t4.y, h4.z*s4.z + t4.z, h4.w*s4.w + t4.w);
    }
    __syncthreads();
    // matmul1: [32x128] @ [128x64] -> r, SiLU
    {
      int ti = tid >> 5, di = tid & 31;
      const float* Wh = genW_h + (size_t)hd*DD*64;
      float a0c[4], a1c[4];
      #pragma unroll
      for (int i = 0; i < 4; ++i) { a0c[i] = 0.f; a1c[i] = 0.f; }
      for (int kk = 0; kk < DD; kk += 4) {
        float2 w0 = *(const float2*)(Wh + (kk+0)*64 + di*2);
        float2 w1 = *(const float2*)(Wh + (kk+1)*64 + di*2);
        float2 w2 = *(const float2*)(Wh + (kk+2)*64 + di*2);
        float2 w3 = *(const float2*)(Wh + (kk+3)*64 + di*2);
        #pragma unroll
        for (int i = 0; i < 4; ++i) {
          float4 a = *(float4*)(am + (ti*4 + i)*136 + kk);
          a0c[i] += a.x*w0.x + a.y*w1.x + a.z*w2.x + a.w*w3.x;
          a1c[i] += a.x*w0.y + a.y*w1.y + a.z*w2.y + a.w*w3.y;
        }
      }
      float2 bh = *(const float2*)(genb_h + hd*64 + di*2);
      #pragma unroll
      for (int i = 0; i < 4; ++i) {
        *(float2*)(rm + (ti*4 + i)*72 + di*2) =
            make_float2(silu_f(a0c[i] + bh.x), silu_f(a1c[i] + bh.y));
      }
    }
    __syncthreads();
    // matmul2: [32x64] @ [64 x d_i] -> out slice
    {
      int d_i = c_dims[hd], off = c_offs[hd];
      int nq = (d_i + 3) >> 2;
      const float* Wo = genW_o + (size_t)hd*64*192;
      for (int t2 = tid; t2 < 8*nq; t2 += 256) {
        int tg = t2 / nq, q = t2 - tg*nq, dc = q*4;
        float acc2[4][4];
        #pragma unroll
        for (int i = 0; i < 4; ++i) { acc2[i][0]=0.f; acc2[i][1]=0.f; acc2[i][2]=0.f; acc2[i][3]=0.f; }
        for (int kk = 0; kk < 64; kk += 4) {
          float4 w0 = *(const float4*)(Wo + (kk+0)*192 + dc);
          float4 w1 = *(const float4*)(Wo + (kk+1)*192 + dc);
          float4 w2 = *(const float4*)(Wo + (kk+2)*192 + dc);
          float4 w3 = *(const float4*)(Wo + (kk+3)*192 + dc);
          #pragma unroll
          for (int i = 0; i < 4; ++i) {
            float4 a = *(float4*)(rm + (tg*4 + i)*72 + kk);
            acc2[i][0] += a.x*w0.x + a.y*w1.x + a.z*w2.x + a.w*w3.x;
            acc2[i][1] += a.x*w0.y + a.y*w1.y + a.z*w2.y + a.w*w3.y;
            acc2[i][2] += a.x*w0.z + a.y*w1.z + a.z*w2.z + a.w*w3.z;
            acc2[i][3] += a.x*w0.w + a.y*w1.w + a.z*w2.w + a.w*w3.w;
          }
        }
        #pragma unroll
        for (int i = 0; i < 4; ++i) {
          int tok = tg*4 + i;
          float* op = out + ((size_t)b*LL + t0 + tok)*NOUTD + off + dc;
          if (dc + 0 < d_i) op[0] = acc2[i][0] + genb_o[hd*192 + dc + 0];
          if (dc + 1 < d_i) op[1] = acc2[i][1] + genb_o[hd*192 + dc + 1];
          if (dc + 2 < d_i) op[2] = acc2[i][2] + genb_o[hd*192 + dc + 2];
          if (dc + 3 < d_i) op[3] = acc2[i][3] + genb_o[hd*192 + dc + 3];
        }
      }
    }
  }
}

// ================= launch =================
extern "C" void kernel_launch(void* const* d_in, const int* in_sizes, int n_in,
                              void* d_out, int out_size, void* d_ws, size_t ws_size,
                              hipStream_t stream) {
  const int*   phone_seq   = (const int*)  d_in[0];
  const int*   singer_id   = (const int*)  d_in[1];
  const int*   language_id = (const int*)  d_in[2];
  const float* f0          = (const float*)d_in[3];
  const float* phone_emb   = (const float*)d_in[4];
  const float* singer_emb  = (const float*)d_in[5];
  const float* lang_emb    = (const float*)d_in[6];
  const float* inW         = (const float*)d_in[7];
  const float* inb         = (const float*)d_in[8];
  const float* inln_g      = (const float*)d_in[9];
  const float* inln_b      = (const float*)d_in[10];
  const float* s4_ln_g     = (const float*)d_in[11];
  const float* s4_ln_b     = (const float*)d_in[12];
  const float* s4_inW      = (const float*)d_in[13];
  const float* s4_inb      = (const float*)d_in[14];
  const float* s4_outW     = (const float*)d_in[15];
  const float* s4_outb     = (const float*)d_in[16];
  const float* lam_re      = (const float*)d_in[17];
  const float* lam_im      = (const float*)d_in[18];
  const float* Bn          = (const float*)d_in[19];
  const float* C_re        = (const float*)d_in[20];
  const float* C_im        = (const float*)d_in[21];
  const float* Dc          = (const float*)d_in[22];
  const float* attn_g      = (const float*)d_in[23];
  const float* attn_lnb    = (const float*)d_in[24];
  const float* attn_w      = (const float*)d_in[25];
  const float* attn_bias   = (const float*)d_in[26];
  const float* gpW         = (const float*)d_in[27];
  const float* gpb         = (const float*)d_in[28];
  const float* genW_s      = (const float*)d_in[29];
  const float* genb_s      = (const float*)d_in[30];
  const float* genW_sh     = (const float*)d_in[31];
  const float* genb_sh     = (const float*)d_in[32];
  const float* genW_h      = (const float*)d_in[33];
  const float* genb_h      = (const float*)d_in[34];
  const float* genW_o      = (const float*)d_in[35];
  const float* genb_o      = (const float*)d_in[36];
  float* ws  = (float*)d_ws;
  float* out = (float*)d_out;

  k0_setup<<<4, 256, 0, stream>>>(s4_ln_g, s4_ln_b, s4_inW, s4_inb,
                                  lam_re, lam_im, Bn, C_re, C_im,
                                  attn_g, attn_lnb, attn_w, attn_bias,
                                  singer_id, language_id, singer_emb, lang_emb, inW, inb, ws);
  k1_input<<<BB*LL/64, 256, 0, stream>>>(phone_seq, f0, phone_emb, inW, inln_g, inln_b, ws);
  for (int ly = 0; ly < 3; ++ly) {
    k2_ln_inproj<<<BB*LL/64, 256, 0, stream>>>(ws, ly);
    k3_conv_out<<<BB*LL/32, 256, 0, stream>>>(ws, s4_outW, s4_outb, Dc, ly, (ly == 2) ? 1 : 0);
  }
  k5b_pool<<<BB*16, 256, 0, stream>>>(ws);
  k5c_cond<<<1, 256, 0, stream>>>(ws, gpW, gpb, genW_s, genb_s, genW_sh, genb_sh);
  k6_heads<<<BB*LL/32, 256, 0, stream>>>(ws, genW_h, genb_h, genW_o, genb_o, out);
}

// Round 2
// 623.215 us; speedup vs baseline: 1.8290x; 1.8290x over previous
//
#include <hip/hip_runtime.h>
#include <math.h>

// ---------------- problem constants ----------------
#define BB 8
#define LL 8192
#define DD 128
#define NCH 8
#define NST 64
#define TAPS 32          // e^{-0.5*32} ~ 1e-7 relative: FIR truncation far below threshold
#define NOUTD 375

// ---------------- MFMA types ----------------
typedef __attribute__((ext_vector_type(8))) short bf16x8;
typedef __attribute__((ext_vector_type(4))) float f32x4;
#define MFMA16(a,b,c) __builtin_amdgcn_mfma_f32_16x16x32_bf16((a),(b),(c),0,0,0)

struct __align__(8) us4 { unsigned short x,y,z,w; };

__device__ __forceinline__ unsigned short f2b(float f) {   // fp32 -> bf16 RNE
  unsigned x = __float_as_uint(f);
  unsigned r = (x + 0x7fffu + ((x >> 16) & 1u)) >> 16;
  return (unsigned short)r;
}
__device__ __forceinline__ float b2f(unsigned short u) {
  return __uint_as_float(((unsigned)u) << 16);
}
__device__ __forceinline__ float silu_f(float x){ return x / (1.f + expf(-x)); }

// ---------------- workspace layout (float offsets) ----------------
static constexpr size_t WS_H      = 0;                             // [B,L,128] fp32 residual
static constexpr size_t WS_LOGITS = WS_H      + (size_t)BB*LL*DD;  // [B,L]
static constexpr size_t WS_SEGM   = WS_LOGITS + (size_t)BB*LL;     // [B,16]
static constexpr size_t WS_SEGS   = WS_SEGM   + BB*16;             // [B,16]
static constexpr size_t WS_SEGV   = WS_SEGS   + BB*16;             // [B,16,128]
static constexpr size_t WS_SCALE  = WS_SEGV   + (size_t)BB*16*DD;  // [7,B,128]
static constexpr size_t WS_SHIFT  = WS_SCALE  + (size_t)7*BB*DD;   // [7,B,128]
static constexpr size_t WS_C1     = WS_SHIFT  + (size_t)7*BB*DD;   // [3,128]
static constexpr size_t WS_C2     = WS_C1     + 3*DD;              // [3,128]
static constexpr size_t WS_KTAB   = WS_C2     + 3*DD;              // [3,8,32]
static constexpr size_t WS_GAW    = WS_KTAB   + 3*NCH*TAPS;        // [128]
static constexpr size_t WS_ASCAL  = WS_GAW    + DD;                // 2 (+pad)
static constexpr size_t WS_BASE   = WS_ASCAL  + 32;                // [B,128]
static constexpr size_t WS_BIAS1  = WS_BASE   + BB*DD;             // [B,448] folded gen bias
// ----- ushort (bf16) regions, float-offset based -----
static constexpr size_t WS_ZB_F   = WS_BIAS1  + (size_t)BB*448;    // [B,L,128] bf16 z
static constexpr size_t WS_WGT_F  = WS_ZB_F   + (size_t)BB*LL*DD/2; // [3,128n,128k] bf16 ln-folded inW^T
static constexpr size_t WS_WOT_F  = WS_WGT_F  + (size_t)3*DD*DD/2;  // [3,128n,128k] bf16 outW^T
static constexpr size_t WS_WO2T_F = WS_WOT_F  + (size_t)3*DD*DD/2;  // [7,192n,64k] bf16 genW_o^T
static constexpr size_t WS_WCT_F  = WS_WO2T_F + (size_t)7*192*64/2; // [B,448n,128k] bf16 folded gen W
static constexpr size_t WS_TOTAL  = WS_WCT_F  + (size_t)BB*448*DD/2; // ~13.0M floats = 52 MB

__device__ __constant__ int c_offs_d[7] = {0, 1, 2, 102, 294, 358, 370};
__device__ __constant__ int c_dims_d[7] = {1, 1, 100, 192, 64, 12, 5};
// 27 n-tiles of GEMM2 (block-diagonal): (head, local col tile)
__device__ __constant__ int t_hd[27] = {0,1,2,2,2,2,2,2,2,3,3,3,3,3,3,3,3,3,3,3,3,4,4,4,4,5,6};
__device__ __constant__ int t_nl[27] = {0,0,0,1,2,3,4,5,6,0,1,2,3,4,5,6,7,8,9,10,11,0,1,2,3,0,0};

// ================= K0: fold weights, tabulate FIR taps, bf16 weight transposes =================
__global__ __launch_bounds__(256) void k0_setup(
    const float* s4_ln_g, const float* s4_ln_b, const float* s4_inW, const float* s4_inb,
    const float* s4_outW,
    const float* lam_re, const float* lam_im, const float* Bn, const float* Cre, const float* Cim,
    const float* attn_g, const float* attn_lnb, const float* attn_w, const float* attn_bias,
    const int* singer_id, const int* language_id,
    const float* singer_emb, const float* lang_emb, const float* inW, const float* inb,
    const float* genW_o, float* ws)
{
  int blk = blockIdx.x, tid = threadIdx.x;
  unsigned short* wgt  = (unsigned short*)(ws + WS_WGT_F);
  unsigned short* wot  = (unsigned short*)(ws + WS_WOT_F);
  unsigned short* wo2t = (unsigned short*)(ws + WS_WO2T_F);
  if (blk < 3) {
    int ly = blk;
    if (tid < DD) {
      int d = tid;
      float c1 = 0.f, c2 = 0.f;
      for (int k = 0; k < DD; ++k) {
        float g = s4_ln_g[ly*DD + k];
        float b = s4_ln_b[ly*DD + k];
        float w = s4_inW[((size_t)ly*DD + k)*DD + d];
        c1 += g * w;
        c2 += b * w;
      }
      ws[WS_C1 + ly*DD + d] = c1;
      ws[WS_C2 + ly*DD + d] = c2 + s4_inb[ly*DD + d];
    }
    // bf16 transposed weights: [n][k]
    for (int o = tid; o < DD*DD; o += 256) {
      int n = o >> 7, k = o & 127;
      wgt[ly*DD*DD + o] = f2b(s4_ln_g[ly*DD + k] * s4_inW[((size_t)ly*DD + k)*DD + n]);
      wot[ly*DD*DD + o] = f2b(s4_outW[((size_t)ly*DD + k)*DD + n]);
    }
    {  // FIR taps: 256 threads = 8 chunks x 32 taps
      int c = tid >> 5, dt = tid & 31;
      const float* lre = lam_re + (ly*NCH + c)*NST;
      const float* lim = lam_im + (ly*NCH + c)*NST;
      const float* bn  = Bn  + (ly*NCH + c)*NST;
      const float* cre = Cre + (ly*NCH + c)*NST;
      const float* cim = Cim + (ly*NCH + c)*NST;
      float td = (float)dt, acc = 0.f;
      for (int n = 0; n < NST; ++n) {
        float e = expf(lre[n]*td);
        float ang = lim[n]*td;
        acc += bn[n]*(cre[n]*cosf(ang) - cim[n]*sinf(ang))*e;
      }
      ws[WS_KTAB + (ly*NCH + c)*TAPS + dt] = acc;
    }
    if (ly == 0 && tid < DD) ws[WS_GAW + tid] = attn_g[tid]*attn_w[tid];
    if (ly == 0 && tid == 0) {
      float c1s = 0.f, c2s = 0.f;
      for (int d = 0; d < DD; ++d) { c1s += attn_g[d]*attn_w[d]; c2s += attn_lnb[d]*attn_w[d]; }
      ws[WS_ASCAL+0] = c1s;
      ws[WS_ASCAL+1] = c2s + attn_bias[0];
    }
  } else {
    for (int o = tid; o < BB*DD; o += 256) {
      int b = o >> 7, d = o & 127;
      int sid = singer_id[b], lid = language_id[b];
      float acc = inb[d];
      for (int j = 0; j < 32; ++j) acc += singer_emb[sid*32 + j]*inW[(64 + j)*DD + d];
      for (int j = 0; j < 16; ++j) acc += lang_emb[lid*16 + j]*inW[(96 + j)*DD + d];
      ws[WS_BASE + o] = acc;
    }
    // genW_o transposed bf16: wo2t[hd][n][k], n<192, k<64
    for (int o = tid; o < 7*192*64; o += 256) {
      int hd = o / (192*64), r = o % (192*64);
      int n = r >> 6, k = r & 63;
      wo2t[o] = f2b(genW_o[((size_t)hd*64 + k)*192 + n]);
    }
  }
}

// ================= K1: embed + input proj + LN + SiLU -> h (fp32) =================
__global__ __launch_bounds__(256) void k1_input(
    const int* phone_seq, const float* f0, const float* phone_emb,
    const float* inW, const float* inln_g, const float* inln_b, float* ws)
{
  __shared__ __align__(16) float pm[64*72];
  __shared__ int   ps[64];
  __shared__ float fv[64];
  int tid = threadIdx.x;
  size_t gbase = (size_t)blockIdx.x * 64;
  if (tid < 64) { ps[tid] = phone_seq[gbase + tid]; fv[tid] = f0[gbase + tid]; }
  __syncthreads();
  #pragma unroll
  for (int j = 0; j < 4; ++j) {
    int idx4 = tid + 256*j;
    int tok = idx4 >> 4, col = idx4 & 15;
    float4 v = *(const float4*)(phone_emb + (size_t)ps[tok]*64 + col*4);
    *(float4*)(pm + tok*72 + col*4) = v;
  }
  __syncthreads();
  int ti = tid >> 5, di = tid & 31, d0 = di*4;
  float acc[8][4];
  #pragma unroll
  for (int i = 0; i < 8; ++i) { acc[i][0]=0.f; acc[i][1]=0.f; acc[i][2]=0.f; acc[i][3]=0.f; }
  for (int kk = 0; kk < 64; kk += 4) {
    float4 w0 = *(const float4*)(inW + (kk+0)*DD + d0);
    float4 w1 = *(const float4*)(inW + (kk+1)*DD + d0);
    float4 w2 = *(const float4*)(inW + (kk+2)*DD + d0);
    float4 w3 = *(const float4*)(inW + (kk+3)*DD + d0);
    #pragma unroll
    for (int i = 0; i < 8; ++i) {
      float4 a = *(float4*)(pm + (ti*8 + i)*72 + kk);
      acc[i][0] += a.x*w0.x + a.y*w1.x + a.z*w2.x + a.w*w3.x;
      acc[i][1] += a.x*w0.y + a.y*w1.y + a.z*w2.y + a.w*w3.y;
      acc[i][2] += a.x*w0.z + a.y*w1.z + a.z*w2.z + a.w*w3.z;
      acc[i][3] += a.x*w0.w + a.y*w1.w + a.z*w2.w + a.w*w3.w;
    }
  }
  float4 w112 = *(const float4*)(inW + 112*DD + d0);
  int b = (int)(gbase >> 13);
  float4 bs  = *(const float4*)(ws + WS_BASE + b*DD + d0);
  float4 lg4 = *(const float4*)(inln_g + d0);
  float4 lb4 = *(const float4*)(inln_b + d0);
  #pragma unroll
  for (int i = 0; i < 8; ++i) {
    int tok = ti*8 + i;
    float fz = fv[tok];
    float y0 = acc[i][0] + fz*w112.x + bs.x;
    float y1 = acc[i][1] + fz*w112.y + bs.y;
    float y2 = acc[i][2] + fz*w112.z + bs.z;
    float y3 = acc[i][3] + fz*w112.w + bs.w;
    float s  = y0+y1+y2+y3;
    float ss = y0*y0+y1*y1+y2*y2+y3*y3;
    #pragma unroll
    for (int m = 16; m >= 1; m >>= 1) { s += __shfl_xor(s, m); ss += __shfl_xor(ss, m); }
    float mean = s * 0.0078125f;
    float var  = ss * 0.0078125f - mean*mean;
    float rstd = rsqrtf(var + 1e-5f);
    y0 = silu_f((y0 - mean)*rstd*lg4.x + lb4.x);
    y1 = silu_f((y1 - mean)*rstd*lg4.y + lb4.y);
    y2 = silu_f((y2 - mean)*rstd*lg4.z + lb4.z);
    y3 = silu_f((y3 - mean)*rstd*lg4.w + lb4.w);
    *(float4*)(ws + WS_H + (gbase + tok)*DD + d0) = make_float4(y0,y1,y2,y3);
  }
}

// ================= K2: folded LN + in_proj via MFMA -> z (bf16) =================
__global__ __launch_bounds__(256) void k2_ln_inproj(float* ws, int ly)
{
  __shared__ __align__(16) unsigned short hm[64*136];   // bf16 A-tile, stride 136 (bank-safe)
  __shared__ float mrs_s[64], rs_s[64];
  int tid = threadIdx.x;
  size_t gbase = (size_t)blockIdx.x * 64;
  const float* hbuf = ws + WS_H;
  float s[8], ss[8];
  #pragma unroll
  for (int j = 0; j < 8; ++j) {
    int idx4 = tid + 256*j;                 // 64 tok x 32 float4
    int tok = idx4 >> 5, c4 = idx4 & 31;
    float4 v = *(const float4*)(hbuf + gbase*DD + (size_t)idx4*4);
    us4 p; p.x = f2b(v.x); p.y = f2b(v.y); p.z = f2b(v.z); p.w = f2b(v.w);
    *(us4*)(hm + tok*136 + c4*4) = p;
    s[j]  = v.x+v.y+v.z+v.w;
    ss[j] = v.x*v.x+v.y*v.y+v.z*v.z+v.w*v.w;
  }
  #pragma unroll
  for (int m = 16; m >= 1; m >>= 1) {
    #pragma unroll
    for (int j = 0; j < 8; ++j) { s[j] += __shfl_xor(s[j], m); ss[j] += __shfl_xor(ss[j], m); }
  }
  if ((tid & 31) == 0) {
    #pragma unroll
    for (int j = 0; j < 8; ++j) {
      int tok = (tid >> 5) + 8*j;
      float mean = s[j]*0.0078125f;
      float var  = ss[j]*0.0078125f - mean*mean;
      float rstd = rsqrtf(var + 1e-5f);
      rs_s[tok] = rstd; mrs_s[tok] = mean*rstd;
    }
  }
  __syncthreads();
  int w = tid >> 6, lane = tid & 63, q = lane >> 4, c = lane & 15;
  int m16 = w*16;
  const unsigned short* wgt = (const unsigned short*)(ws + WS_WGT_F) + ly*DD*DD;
  bf16x8 aF[4];
  #pragma unroll
  for (int kk = 0; kk < 4; ++kk)
    aF[kk] = *(const bf16x8*)(hm + (m16 + c)*136 + kk*32 + q*8);
  float rsv[4], mrv[4];
  #pragma unroll
  for (int r = 0; r < 4; ++r) { int row = m16 + q*4 + r; rsv[r] = rs_s[row]; mrv[r] = mrs_s[row]; }
  unsigned short* zb = (unsigned short*)(ws + WS_ZB_F);
  #pragma unroll
  for (int nt = 0; nt < 8; ++nt) {
    f32x4 acc = {0.f,0.f,0.f,0.f};
    #pragma unroll
    for (int kk = 0; kk < 4; ++kk) {
      bf16x8 bF = *(const bf16x8*)(wgt + (nt*16 + c)*DD + kk*32 + q*8);
      acc = MFMA16(aF[kk], bF, acc);
    }
    int col = nt*16 + c;
    float c1v = ws[WS_C1 + ly*DD + col];
    float c2v = ws[WS_C2 + ly*DD + col];
    #pragma unroll
    for (int r = 0; r < 4; ++r) {
      float zv = rsv[r]*acc[r] - mrv[r]*c1v + c2v;
      zb[(gbase + m16 + q*4 + r)*DD + col] = f2b(zv);
    }
  }
}

// ================= K3: FIR conv (fp32) + skip + MFMA out_proj + SiLU + residual (+logits) =====
__global__ __launch_bounds__(256) void k3_conv_out(
    float* ws, const float* s4_outb, const float* Dc, int ly, int do_logits)
{
  __shared__ __align__(16) unsigned short zw[128*128];  // 64-tok tile + 32 halo each side (bf16)
  __shared__ __align__(16) unsigned short ym[64*136];   // bf16 A-tile for out_proj
  __shared__ float k2t[8*64];
  __shared__ float dcs[8];
  int tid = threadIdx.x, blk = blockIdx.x;
  int b  = blk >> 7;
  int t0 = (blk & 127) * 64;
  const unsigned short* zbp = (const unsigned short*)(ws + WS_ZB_F);
  #pragma unroll
  for (int j = 0; j < 8; ++j) {
    int idx8 = tid + 256*j;            // 128 tok x 16 ushort8
    int tok = idx8 >> 4, c8 = idx8 & 15;
    int t = t0 - 32 + tok;
    bf16x8 v = {0,0,0,0,0,0,0,0};
    if (t >= 0 && t < LL) v = *(const bf16x8*)(zbp + ((size_t)b*LL + t)*DD + c8*8);
    *(bf16x8*)(zw + tok*DD + c8*8) = v;
  }
  for (int o = tid; o < 512; o += 256) {     // K2[j]: j=-31..32 -> m=0..63
    int c = o >> 6, m = o & 63;
    int idx = (m <= 31) ? (31 - m) : (m - 32);
    k2t[o] = ws[WS_KTAB + (ly*NCH + c)*TAPS + idx];
  }
  if (tid < 8) dcs[tid] = Dc[ly*NCH + tid];
  __syncthreads();
  // conv: 2 passes, thread = (token half16, channel)
  #pragma unroll
  for (int p = 0; p < 2; ++p) {
    int half = p*2 + (tid >> 7), ch = tid & 127, cx = ch >> 4;
    int base = 1 + half*16;
    float ring[16], accv[16];
    #pragma unroll
    for (int x = 0; x < 16; ++x) { ring[x] = b2f(zw[(base + x)*DD + ch]); accv[x] = 0.f; }
    #pragma unroll
    for (int m = 0; m < 64; ++m) {
      float kf = k2t[cx*64 + m];
      #pragma unroll
      for (int i = 0; i < 16; ++i) accv[i] += kf * ring[(m + i) & 15];
      if (m < 63) ring[m & 15] = b2f(zw[(base + m + 16)*DD + ch]);
    }
    float dcv = dcs[cx];
    #pragma unroll
    for (int i = 0; i < 16; ++i) {
      int tl = half*16 + i;
      ym[tl*136 + ch] = f2b(accv[i] + dcv * b2f(zw[(32 + tl)*DD + ch]));
    }
  }
  __syncthreads();
  // MFMA out_proj: wave w -> rows w*16..+15
  int w = tid >> 6, lane = tid & 63, q = lane >> 4, c = lane & 15;
  int m16 = w*16;
  const unsigned short* wot = (const unsigned short*)(ws + WS_WOT_F) + ly*DD*DD;
  bf16x8 aF[4];
  #pragma unroll
  for (int kk = 0; kk < 4; ++kk)
    aF[kk] = *(const bf16x8*)(ym + (m16 + c)*136 + kk*32 + q*8);
  float* hbuf = ws + WS_H;
  float c1s = ws[WS_ASCAL+0], c2s = ws[WS_ASCAL+1];
  float sr[4] = {0,0,0,0}, ssr[4] = {0,0,0,0}, dtr[4] = {0,0,0,0};
  #pragma unroll
  for (int nt = 0; nt < 8; ++nt) {
    f32x4 acc = {0.f,0.f,0.f,0.f};
    #pragma unroll
    for (int kk = 0; kk < 4; ++kk) {
      bf16x8 bF = *(const bf16x8*)(wot + (nt*16 + c)*DD + kk*32 + q*8);
      acc = MFMA16(aF[kk], bF, acc);
    }
    int col = nt*16 + c;
    float ob = s4_outb[ly*DD + col];
    float gw = ws[WS_GAW + col];
    #pragma unroll
    for (int r = 0; r < 4; ++r) {
      size_t gofs = ((size_t)b*LL + t0 + m16 + q*4 + r)*DD + col;
      float hold = hbuf[gofs];
      float hn = hold + silu_f(acc[r] + ob);
      hbuf[gofs] = hn;
      if (do_logits) { sr[r] += hn; ssr[r] += hn*hn; dtr[r] += hn*gw; }
    }
  }
  if (do_logits) {
    #pragma unroll
    for (int m = 8; m >= 1; m >>= 1) {   // reduce across 16-lane quad (cols)
      #pragma unroll
      for (int r = 0; r < 4; ++r) {
        sr[r]  += __shfl_xor(sr[r],  m);
        ssr[r] += __shfl_xor(ssr[r], m);
        dtr[r] += __shfl_xor(dtr[r], m);
      }
    }
    if (c < 4) {
      int r = c;
      float mean = sr[r]*0.0078125f;
      float var  = ssr[r]*0.0078125f - mean*mean;
      float rstd = rsqrtf(var + 1e-5f);
      ws[WS_LOGITS + (size_t)b*LL + t0 + m16 + q*4 + r] = rstd*dtr[r] - mean*rstd*c1s + c2s;
    }
  }
}

// ================= K5b: segmented softmax + weighted pool partials =================
__global__ __launch_bounds__(256) void k5b_pool(float* ws)
{
  int blk = blockIdx.x, tid = threadIdx.x;
  int b = blk >> 4, seg = blk & 15;
  const float* lg = ws + WS_LOGITS + (size_t)b*LL + seg*512;
  __shared__ float ev[512];
  __shared__ float red[4], red2[4];
  __shared__ float vr[2][128];
  float a0 = lg[tid], a1 = lg[tid + 256];
  float mx = fmaxf(a0, a1);
  #pragma unroll
  for (int m = 32; m >= 1; m >>= 1) mx = fmaxf(mx, __shfl_xor(mx, m));
  if ((tid & 63) == 0) red[tid >> 6] = mx;
  __syncthreads();
  float M = fmaxf(fmaxf(red[0], red[1]), fmaxf(red[2], red[3]));
  float e0 = expf(a0 - M), e1 = expf(a1 - M);
  ev[tid] = e0; ev[tid + 256] = e1;
  float s = e0 + e1;
  #pragma unroll
  for (int m = 32; m >= 1; m >>= 1) s += __shfl_xor(s, m);
  if ((tid & 63) == 0) red2[tid >> 6] = s;
  __syncthreads();
  float S = red2[0] + red2[1] + red2[2] + red2[3];
  int ls = tid >> 7, d = tid & 127;
  const float* hb = ws + WS_H + ((size_t)b*LL + seg*512)*DD;
  float acc = 0.f;
  for (int jj = 0; jj < 256; ++jj) {
    int tok = jj*2 + ls;
    acc += ev[tok] * hb[(size_t)tok*DD + d];
  }
  vr[ls][d] = acc;
  __syncthreads();
  if (tid < 128) ws[WS_SEGV + (size_t)(b*16 + seg)*DD + tid] = vr[0][tid] + vr[1][tid];
  if (tid == 0) { ws[WS_SEGM + b*16 + seg] = M; ws[WS_SEGS + b*16 + seg] = S; }
}

// ================= K5c: combine pool, g, FiLM scale/shift =================
__global__ __launch_bounds__(256) void k5c_cond(
    float* ws, const float* gpW, const float* gpb,
    const float* genW_s, const float* genb_s, const float* genW_sh, const float* genb_sh)
{
  __shared__ float gpre[BB*DD];
  __shared__ float gg[BB*32];
  __shared__ float Ms[BB], Ss[BB];
  int tid = threadIdx.x;
  if (tid < BB) {
    int b = tid;
    float M = -1e30f;
    for (int sg = 0; sg < 16; ++sg) M = fmaxf(M, ws[WS_SEGM + b*16 + sg]);
    float S = 0.f;
    for (int sg = 0; sg < 16; ++sg) S += ws[WS_SEGS + b*16 + sg]*expf(ws[WS_SEGM + b*16 + sg] - M);
    Ms[b] = M; Ss[b] = S;
  }
  __syncthreads();
  for (int o = tid; o < BB*DD; o += 256) {
    int b = o >> 7, d = o & 127;
    float V = 0.f;
    for (int sg = 0; sg < 16; ++sg)
      V += ws[WS_SEGV + (size_t)(b*16 + sg)*DD + d]*expf(ws[WS_SEGM + b*16 + sg] - Ms[b]);
    gpre[o] = V / Ss[b];
  }
  __syncthreads();
  {
    int b = tid >> 5, c = tid & 31;
    float acc = gpb[c];
    for (int k = 0; k < DD; ++k) acc += gpre[b*DD + k]*gpW[k*32 + c];
    gg[tid] = acc;
  }
  __syncthreads();
  for (int o = tid; o < 7*BB*DD; o += 256) {
    int hd = o >> 10, r = o & 1023, b = r >> 7, d = r & 127;
    float sc = genb_s[hd*DD + d], sh = genb_sh[hd*DD + d];
    for (int c = 0; c < 32; ++c) {
      float g = gg[b*32 + c];
      sc += g*genW_s[((size_t)hd*32 + c)*DD + d];
      sh += g*genW_sh[((size_t)hd*32 + c)*DD + d];
    }
    ws[WS_SCALE + o] = sc;
    ws[WS_SHIFT + o] = sh;
  }
}

// ================= K5d: build folded generator weights Wcat (bf16) + bias1 =================
__global__ __launch_bounds__(256) void k5d_fold(float* ws, const float* genW_h, const float* genb_h)
{
  int blk = blockIdx.x, tid = threadIdx.x;
  int hd = blk >> 3, b = blk & 7;
  const float* sc = ws + WS_SCALE + (size_t)hd*BB*DD + b*DD;
  const float* sh = ws + WS_SHIFT + (size_t)hd*BB*DD + b*DD;
  const float* Wh = genW_h + (size_t)hd*DD*64;
  unsigned short* wct = (unsigned short*)(ws + WS_WCT_F);
  for (int o = tid; o < 64*DD; o += 256) {
    int j = o >> 7, k = o & 127;
    wct[((size_t)b*448 + hd*64 + j)*DD + k] = f2b(sc[k]*Wh[(size_t)k*64 + j]);
  }
  if (tid < 64) {
    int j = tid;
    float a = genb_h[hd*64 + j];
    for (int k = 0; k < DD; ++k) a += sh[k]*Wh[(size_t)k*64 + j];
    ws[WS_BIAS1 + b*448 + hd*64 + j] = a;
  }
}

// ================= K6: generator heads as two MFMA GEMMs =================
__global__ __launch_bounds__(256) void k6_heads(float* ws, const float* genb_o, float* out)
{
  __shared__ __align__(16) unsigned short hm[32*136];   // bf16 h tile
  __shared__ __align__(16) unsigned short rm[32*456];   // bf16 r tile (448 + pad)
  int tid = threadIdx.x, blk = blockIdx.x;
  int b = blk >> 8, t0 = (blk & 255)*32;
  const float* hb = ws + WS_H + ((size_t)b*LL + t0)*DD;
  #pragma unroll
  for (int j = 0; j < 4; ++j) {
    int idx4 = tid + 256*j;                 // 32 tok x 32 float4
    int tok = idx4 >> 5, c4 = idx4 & 31;
    float4 v = *(const float4*)(hb + (size_t)idx4*4);
    us4 p; p.x = f2b(v.x); p.y = f2b(v.y); p.z = f2b(v.z); p.w = f2b(v.w);
    *(us4*)(hm + tok*136 + c4*4) = p;
  }
  __syncthreads();
  int w = tid >> 6, lane = tid & 63, q = lane >> 4, c = lane & 15;
  int m16 = (w & 1)*16, nh = w >> 1;
  // ---- GEMM1: [32x128] @ Wcat_b^T[448][128] -> silu -> rm ----
  {
    bf16x8 aF[4];
    #pragma unroll
    for (int kk = 0; kk < 4; ++kk)
      aF[kk] = *(const bf16x8*)(hm + (m16 + c)*136 + kk*32 + q*8);
    const unsigned short* wct = (const unsigned short*)(ws + WS_WCT_F) + (size_t)b*448*DD;
    for (int ntl = 0; ntl < 14; ++ntl) {
      int nt = nh*14 + ntl;
      f32x4 acc = {0.f,0.f,0.f,0.f};
      #pragma unroll
      for (int kk = 0; kk < 4; ++kk) {
        bf16x8 bF = *(const bf16x8*)(wct + ((size_t)nt*16 + c)*DD + kk*32 + q*8);
        acc = MFMA16(aF[kk], bF, acc);
      }
      int col = nt*16 + c;
      float bias = ws[WS_BIAS1 + b*448 + col];
      #pragma unroll
      for (int r = 0; r < 4; ++r)
        rm[(m16 + q*4 + r)*456 + col] = f2b(silu_f(acc[r] + bias));
    }
  }
  __syncthreads();
  // ---- GEMM2: block-diagonal [32x448] @ Wo -> out [32x375] ----
  {
    const unsigned short* wo2t = (const unsigned short*)(ws + WS_WO2T_F);
    int i0 = (nh == 0) ? 0 : 14;
    int i1 = (nh == 0) ? 14 : 27;
    for (int i = i0; i < i1; ++i) {
      int hd = t_hd[i], nl = t_nl[i];
      bf16x8 aF0 = *(const bf16x8*)(rm + (m16 + c)*456 + hd*64 + q*8);
      bf16x8 aF1 = *(const bf16x8*)(rm + (m16 + c)*456 + hd*64 + 32 + q*8);
      f32x4 acc = {0.f,0.f,0.f,0.f};
      bf16x8 bF0 = *(const bf16x8*)(wo2t + ((size_t)hd*192 + nl*16 + c)*64 + q*8);
      bf16x8 bF1 = *(const bf16x8*)(wo2t + ((size_t)hd*192 + nl*16 + c)*64 + 32 + q*8);
      acc = MFMA16(aF0, bF0, acc);
      acc = MFMA16(aF1, bF1, acc);
      int cl = nl*16 + c;
      int di = c_dims_d[hd];
      if (cl < di) {
        float bo = genb_o[hd*192 + cl];
        #pragma unroll
        for (int r = 0; r < 4; ++r)
          out[((size_t)b*LL + t0 + m16 + q*4 + r)*NOUTD + c_offs_d[hd] + cl] = acc[r] + bo;
      }
    }
  }
}

// ================= launch =================
extern "C" void kernel_launch(void* const* d_in, const int* in_sizes, int n_in,
                              void* d_out, int out_size, void* d_ws, size_t ws_size,
                              hipStream_t stream) {
  const int*   phone_seq   = (const int*)  d_in[0];
  const int*   singer_id   = (const int*)  d_in[1];
  const int*   language_id = (const int*)  d_in[2];
  const float* f0          = (const float*)d_in[3];
  const float* phone_emb   = (const float*)d_in[4];
  const float* singer_emb  = (const float*)d_in[5];
  const float* lang_emb    = (const float*)d_in[6];
  const float* inW         = (const float*)d_in[7];
  const float* inb         = (const float*)d_in[8];
  const float* inln_g      = (const float*)d_in[9];
  const float* inln_b      = (const float*)d_in[10];
  const float* s4_ln_g     = (const float*)d_in[11];
  const float* s4_ln_b     = (const float*)d_in[12];
  const float* s4_inW      = (const float*)d_in[13];
  const float* s4_inb      = (const float*)d_in[14];
  const float* s4_outW     = (const float*)d_in[15];
  const float* s4_outb     = (const float*)d_in[16];
  const float* lam_re      = (const float*)d_in[17];
  const float* lam_im      = (const float*)d_in[18];
  const float* Bn          = (const float*)d_in[19];
  const float* C_re        = (const float*)d_in[20];
  const float* C_im        = (const float*)d_in[21];
  const float* Dc          = (const float*)d_in[22];
  const float* attn_g      = (const float*)d_in[23];
  const float* attn_lnb    = (const float*)d_in[24];
  const float* attn_w      = (const float*)d_in[25];
  const float* attn_bias   = (const float*)d_in[26];
  const float* gpW         = (const float*)d_in[27];
  const float* gpb         = (const float*)d_in[28];
  const float* genW_s      = (const float*)d_in[29];
  const float* genb_s      = (const float*)d_in[30];
  const float* genW_sh     = (const float*)d_in[31];
  const float* genb_sh     = (const float*)d_in[32];
  const float* genW_h      = (const float*)d_in[33];
  const float* genb_h      = (const float*)d_in[34];
  const float* genW_o      = (const float*)d_in[35];
  const float* genb_o      = (const float*)d_in[36];
  float* ws  = (float*)d_ws;
  float* out = (float*)d_out;

  k0_setup<<<4, 256, 0, stream>>>(s4_ln_g, s4_ln_b, s4_inW, s4_inb, s4_outW,
                                  lam_re, lam_im, Bn, C_re, C_im,
                                  attn_g, attn_lnb, attn_w, attn_bias,
                                  singer_id, language_id, singer_emb, lang_emb, inW, inb,
                                  genW_o, ws);
  k1_input<<<BB*LL/64, 256, 0, stream>>>(phone_seq, f0, phone_emb, inW, inln_g, inln_b, ws);
  for (int ly = 0; ly < 3; ++ly) {
    k2_ln_inproj<<<BB*LL/64, 256, 0, stream>>>(ws, ly);
    k3_conv_out<<<BB*LL/64, 256, 0, stream>>>(ws, s4_outb, Dc, ly, (ly == 2) ? 1 : 0);
  }
  k5b_pool<<<BB*16, 256, 0, stream>>>(ws);
  k5c_cond<<<1, 256, 0, stream>>>(ws, gpW, gpb, genW_s, genb_s, genW_sh, genb_sh);
  k5d_fold<<<56, 256, 0, stream>>>(ws, genW_h, genb_h);
  k6_heads<<<BB*LL/32, 256, 0, stream>>>(ws, genb_o, out);
}